// Round 11
// baseline (591.106 us; speedup 1.0000x reference)
//
#include <hip/hip_runtime.h>
#include <hip/hip_bf16.h>

#define B_ 4
#define N_ 8192
#define KNN 16
#define BN_ (B_*N_)      // 32768
#define NPOS (BN_*KNN)   // 524288

typedef __attribute__((ext_vector_type(8))) short bf16x8;
typedef __attribute__((ext_vector_type(4))) float f32x4;

static __device__ __forceinline__ unsigned short f2bf(float f) {
  union { float f; unsigned u; } v; v.f = f;
  unsigned r = v.u + 0x7fff + ((v.u >> 16) & 1);
  return (unsigned short)(r >> 16);
}
static __device__ __forceinline__ float lk(float x) { return x >= 0.f ? x : 0.2f*x; }
static __device__ __forceinline__ unsigned pk2(float a, float b) {
  return (unsigned)f2bf(a) | ((unsigned)f2bf(b) << 16);
}

// ---------------- prep: pts4 = (x,y,z,|p|^2) ----------------
__global__ void k_prep(const float* __restrict__ xyz, float4* __restrict__ pts4) {
  int i = blockIdx.x * 256 + threadIdx.x;
  if (i >= BN_) return;
  int b = i >> 13, n = i & (N_-1);
  const float* p = xyz + b*3*N_;
  float x = p[n], y = p[N_+n], z = p[2*N_+n];
  float xx = fmaf(z, z, fmaf(y, y, x*x));
  pts4[i] = make_float4(x, y, z, xx);
}

// ------- convert ALL weights to bf16, PRE-SWIZZLED LDS images -------
__global__ void k_wcvt(const float* __restrict__ w_sc, const float* __restrict__ w_a,
                       const float* __restrict__ w_b, const float* __restrict__ w_c,
                       const float* __restrict__ p1a, const float* __restrict__ p1sc,
                       const float* __restrict__ p1b, const float* __restrict__ p1c,
                       unsigned short* __restrict__ out) {
  int i = blockIdx.x*256 + threadIdx.x;
  if (i >= 61440) return;
  if (i < 49152) {
    int x = i*2;                            // byte offset in p2 image
    const float* w; int base, K2;
    if (x < 32768)      { w = w_sc; base = 0;     K2 = 256; }
    else if (x < 49152) { w = w_a;  base = 32768; K2 = 256; }
    else if (x < 65536) { w = w_b;  base = 49152; K2 = 128; }
    else                { w = w_c;  base = 65536; K2 = 256; }
    int off = x - base;
    int row = off / K2;
    int colb = (off & (K2-1)) ^ ((row & 7) << 4);
    int k = colb >> 1;
    out[i] = f2bf(w[row*(K2 >> 1) + k]);
  } else {
    int e = i - 49152;                      // 0..12287
    float val; int byteoff;
    if (e < 2048) {               // Wa 64x32 (64B rows)
      int row = e >> 5, k = e & 31;
      val = (k < 10) ? p1a[row*10 + k] : 0.f;
      byteoff = row*64 + ((2*k) ^ ((row & 3) << 4));
    } else if (e < 4096) {        // Wsc 64x32
      int le = e - 2048, row = le >> 5, k = le & 31;
      val = (k < 10) ? p1sc[row*10 + k] : 0.f;
      byteoff = 4096 + row*64 + ((2*k) ^ ((row & 3) << 4));
    } else if (e < 8192) {        // Wb 64x64 (128B rows)
      int le = e - 4096, row = le >> 6, k = le & 63;
      val = p1b[row*64 + k];
      byteoff = 8192 + row*128 + ((2*k) ^ ((row & 7) << 4));
    } else {                      // Wc 64x64
      int le = e - 8192, row = le >> 6, k = le & 63;
      val = p1c[row*64 + k];
      byteoff = 16384 + row*128 + ((2*k) ^ ((row & 7) << 4));
    }
    out[49152 + (byteoff >> 1)] = f2bf(val);
  }
}

// ================= GRID KNN =================
#define GRES 32
#define GC (GRES*GRES*GRES)   // 32768 cells/batch
#define GH 0.25f

__global__ void k_zero(int* __restrict__ p, int n) {
  int i = blockIdx.x*256 + threadIdx.x;
  if (i < n) p[i] = 0;
}

__global__ void k_cell(const float4* __restrict__ pts4, int* __restrict__ hist,
                       int* __restrict__ cid) {
  int i = blockIdx.x*256 + threadIdx.x;
  if (i >= BN_) return;
  float4 p = pts4[i];
  int cx = min(max((int)floorf((p.x + 4.f)*4.f), 0), GRES-1);
  int cy = min(max((int)floorf((p.y + 4.f)*4.f), 0), GRES-1);
  int cz = min(max((int)floorf((p.z + 4.f)*4.f), 0), GRES-1);
  int c = (cz*GRES + cy)*GRES + cx;
  cid[i] = c;
  atomicAdd(&hist[(i >> 13)*GC + c], 1);
}

__global__ __launch_bounds__(1024) void k_scan(const int* __restrict__ hist,
                                               int* __restrict__ cellStart) {
  __shared__ int ps[1024];
  int b = blockIdx.x, t = threadIdx.x;
  const int* h = hist + b*GC;
  int* cs = cellStart + b*(GC+1);
  int loc[32]; int sum = 0;
  #pragma unroll
  for (int i = 0; i < 32; ++i) { loc[i] = sum; sum += h[t*32 + i]; }
  ps[t] = sum;
  __syncthreads();
  for (int off = 1; off < 1024; off <<= 1) {
    int v = (t >= off) ? ps[t - off] : 0;
    __syncthreads();
    ps[t] += v;
    __syncthreads();
  }
  int excl = ps[t] - sum;
  #pragma unroll
  for (int i = 0; i < 32; ++i) cs[t*32 + i] = excl + loc[i];
  if (t == 1023) cs[GC] = excl + sum;   // = 8192
}

__global__ void k_scatter(const float4* __restrict__ pts4, const int* __restrict__ cid,
                          const int* __restrict__ cellStart, int* __restrict__ ctr,
                          float4* __restrict__ pts_sorted, int* __restrict__ idx_sorted) {
  int i = blockIdx.x*256 + threadIdx.x;
  if (i >= BN_) return;
  int b = i >> 13, c = cid[i];
  int pos = cellStart[b*(GC+1) + c] + atomicAdd(&ctr[b*GC + c], 1);
  int g = (b << 13) + pos;
  pts_sorted[g] = pts4[i];
  idx_sorted[g] = i & (N_-1);
}

// u64 key = (f32bits(d2)<<32)|idx -> ascending u64 == lexicographic (d2, idx).
static __device__ __forceinline__ unsigned long long bitonic64(
    unsigned long long key, int lane) {
  #pragma unroll
  for (int size = 2; size <= 64; size <<= 1) {
    #pragma unroll
    for (int stride = size >> 1; stride >= 1; stride >>= 1) {
      unsigned long long ok = __shfl_xor((long long)key, stride);
      bool up = ((lane & size) == 0);
      bool keepmin = (((lane & stride) == 0) == up);
      bool oless = ok < key;
      if (oless == keepmin) key = ok;
    }
  }
  return key;
}

// ONE WAVE PER QUERY (cell-sorted order): 64-wide coalesced range scans,
// ballot-append to LDS buffer, bitonic-64 compaction when >=48 pending.
// Wave-uniform traversal (one query per wave). 32768 waves -> 8/SIMD.
__global__ __launch_bounds__(256) void k_knng(
    const float4* __restrict__ pts_sorted, const int* __restrict__ idx_sorted,
    const int* __restrict__ cellStart, int* __restrict__ knn) {
  __shared__ unsigned long long buf[4][112];
  const int lane = threadIdx.x & 63;
  const int wv   = threadIdx.x >> 6;
  int g = blockIdx.x*4 + wv;              // sorted query index 0..32767
  int b = g >> 13;
  const float4* __restrict__ PS = pts_sorted + (b << 13);
  const int* __restrict__ IS = idx_sorted + (b << 13);
  const int* __restrict__ CS = cellStart + b*(GC+1);
  int sq = g & (N_-1);
  float4 me = PS[sq];
  int oq = IS[sq];
  int cx = min(max((int)floorf((me.x + 4.f)*4.f), 0), GRES-1);
  int cy = min(max((int)floorf((me.y + 4.f)*4.f), 0), GRES-1);
  int cz = min(max((int)floorf((me.z + 4.f)*4.f), 0), GRES-1);

  unsigned long long topk = 0x7F800000FFFFFFFFull;  // lanes 0..15: sorted keys
  float worst = __builtin_inff();
  int cnt = 0;
  unsigned long long* __restrict__ bw = buf[wv];

#define COMPACT() {                                                           \
    int base = 0;                                                             \
    while (cnt > 0) {                                                         \
      int c2 = cnt > 48 ? 48 : cnt;                                           \
      unsigned long long e = (lane < 16) ? topk                               \
        : ((lane - 16) < c2 ? bw[base + lane - 16] : ~0ull);                  \
      topk = bitonic64(e, lane);                                              \
      base += c2; cnt -= c2;                                                  \
    }                                                                         \
    unsigned long long k15 = __shfl((long long)topk, 15);                     \
    worst = __uint_as_float((unsigned)(k15 >> 32));                           \
  }

#define WSCAN(st_, en_)                                                       \
  for (int j0 = (st_); j0 < (en_); j0 += 64) {                                \
    int j = j0 + lane;                                                        \
    bool okl = j < (en_);                                                     \
    int jj = okl ? j : (en_) - 1;                                             \
    float4 c = PS[jj];                                                        \
    int id = IS[jj];                                                          \
    float dot = fmaf(me.z, c.z, fmaf(me.y, c.y, me.x*c.x));                   \
    float d2 = me.w + fmaf(-2.f, dot, c.w);                                   \
    bool hit = okl && (d2 <= worst);                                          \
    unsigned long long m = __ballot(hit);                                     \
    if (m) {                                                                  \
      int prefix = __builtin_amdgcn_mbcnt_hi((unsigned)(m >> 32),             \
                    __builtin_amdgcn_mbcnt_lo((unsigned)m, 0));               \
      if (hit)                                                                \
        bw[cnt + prefix] =                                                    \
          ((unsigned long long)__float_as_uint(d2) << 32) | (unsigned)id;     \
      cnt += __popcll(m);                                                     \
      if (cnt >= 48) COMPACT()                                                \
    }                                                                         \
  }

  for (int s = 0; s < GRES; ++s) {
    if (s >= 1) {
      float bnd = (float)(s - 1) * GH;
      if (bnd*bnd > worst) break;       // wave-uniform (worst uniform)
    }
    int zlo = max(cz - s, 0), zhi = min(cz + s, GRES-1);
    for (int z = zlo; z <= zhi; ++z) {
      int adz = (z > cz) ? (z - cz) : (cz - z);
      int ylo = max(cy - s, 0), yhi = min(cy + s, GRES-1);
      for (int y = ylo; y <= yhi; ++y) {
        int ady = (y > cy) ? (y - cy) : (cy - y);
        int rb = (z*GRES + y)*GRES;
        if (adz == s || ady == s) {
          int xlo = max(cx - s, 0), xhi = min(cx + s, GRES-1);
          int st = CS[rb + xlo], en = CS[rb + xhi + 1];
          WSCAN(st, en)
        } else {
          int x0 = cx - s, x1 = cx + s;
          if (x0 >= 0) { int st = CS[rb + x0], en = CS[rb + x0 + 1]; WSCAN(st, en) }
          if (x1 <= GRES-1) { int st = CS[rb + x1], en = CS[rb + x1 + 1]; WSCAN(st, en) }
        }
      }
    }
  }
  if (cnt > 0) COMPACT()
#undef WSCAN
#undef COMPACT
  if (lane < 16)
    knn[((size_t)((b << 13) + oq))*16 + lane] = (int)(unsigned)(topk & 0xffffffffu);
}

// ---------------- phase-1 conv-res on MFMA, PERSISTENT (4 tiles/block) ----------------
__global__ __launch_bounds__(512, 4) void k_p1(
    const float4* __restrict__ pts4, const int* __restrict__ knn,
    const unsigned short* __restrict__ wbf,
    const float* __restrict__ a_b, const float* __restrict__ b_b,
    const float* __restrict__ c_b, const float* __restrict__ sc_b,
    unsigned short* __restrict__ X, unsigned short* __restrict__ XM) {
  __shared__ __align__(16) unsigned short Ws1[12288];  // 24 KB swizzled weights
  __shared__ __align__(16) unsigned short Fs[8192];    // 16 KB features
  __shared__ __align__(16) unsigned short Hr[16384];   // 32 KB wave H regions
  const int tid = threadIdx.x;
  const int lane = tid & 63, wv = tid >> 6;
  const int colr = lane & 15, kq = lane >> 4;

  #pragma unroll
  for (int j = 0; j < 3; ++j) {
    int c = j*512 + tid;
    ((uint4*)Ws1)[c] = ((const uint4*)(wbf + 49152))[c];
  }
  const char* WS = (const char*)Ws1;
  char* H = (char*)Hr + wv*4096;

  for (int tile = 0; tile < 4; ++tile) {
    const int bn0 = (blockIdx.x*4 + tile) * 16;
    __syncthreads();
    if (tid < 256) {
      int bnl = tid >> 4, kk = tid & 15;
      int bn = bn0 + bnl;
      int b = bn >> 13;
      float4 cp = pts4[bn];
      int nid = knn[bn*16 + kk];
      float4 np = pts4[(b << 13) + nid];
      float rx = np.x - cp.x, ry = np.y - cp.y, rz = np.z - cp.z;
      float dist = sqrtf(fmaf(rz, rz, fmaf(ry, ry, rx*rx)) + 1e-12f);
      unsigned short row[32];
      row[0]=f2bf(cp.x); row[1]=f2bf(cp.y); row[2]=f2bf(cp.z);
      row[3]=f2bf(np.x); row[4]=f2bf(np.y); row[5]=f2bf(np.z);
      row[6]=f2bf(rx);   row[7]=f2bf(ry);   row[8]=f2bf(rz);   row[9]=f2bf(dist);
      #pragma unroll
      for (int j = 10; j < 32; ++j) row[j] = 0;
      int wvp = tid >> 5, posl = tid & 31;
      char* dst = (char*)Fs + wvp*2048 + posl*64;
      #pragma unroll
      for (int c = 0; c < 4; ++c)
        *(uint4*)(dst + ((c*16) ^ ((posl&3)<<4))) = *(const uint4*)(row + c*8);
    }
    __syncthreads();

    bf16x8 bfr[2];
    #pragma unroll
    for (int ct = 0; ct < 2; ++ct) {
      int posl = ct*16 + colr;
      bfr[ct] = *(const bf16x8*)((const char*)Fs + wv*2048 + posl*64 + ((kq*16) ^ ((posl&3)<<4)));
    }

    f32x4 acc[4][2];
    #pragma unroll
    for (int mt = 0; mt < 4; ++mt) {
      int r0 = mt*16 + kq*4;
      #pragma unroll
      for (int r = 0; r < 4; ++r) {
        float bia = c_b[r0+r] + sc_b[r0+r];
        acc[mt][0][r] = bia; acc[mt][1][r] = bia;
      }
    }
    #pragma unroll
    for (int mt = 0; mt < 4; ++mt) {
      int row = mt*16 + colr;
      bf16x8 w = *(const bf16x8*)(WS + 4096 + row*64 + ((kq*16) ^ ((row&3)<<4)));
      acc[mt][0] = __builtin_amdgcn_mfma_f32_16x16x32_bf16(w, bfr[0], acc[mt][0], 0, 0, 0);
      acc[mt][1] = __builtin_amdgcn_mfma_f32_16x16x32_bf16(w, bfr[1], acc[mt][1], 0, 0, 0);
    }

    f32x4 ha[4][2];
    #pragma unroll
    for (int mt = 0; mt < 4; ++mt) {
      int r0 = mt*16 + kq*4;
      #pragma unroll
      for (int r = 0; r < 4; ++r) { ha[mt][0][r] = a_b[r0+r]; ha[mt][1][r] = a_b[r0+r]; }
    }
    #pragma unroll
    for (int mt = 0; mt < 4; ++mt) {
      int row = mt*16 + colr;
      bf16x8 w = *(const bf16x8*)(WS + row*64 + ((kq*16) ^ ((row&3)<<4)));
      ha[mt][0] = __builtin_amdgcn_mfma_f32_16x16x32_bf16(w, bfr[0], ha[mt][0], 0, 0, 0);
      ha[mt][1] = __builtin_amdgcn_mfma_f32_16x16x32_bf16(w, bfr[1], ha[mt][1], 0, 0, 0);
    }

    #pragma unroll
    for (int mt = 0; mt < 4; ++mt) {
      int ch2 = (mt*16 + kq*4) * 2;
      #pragma unroll
      for (int ct = 0; ct < 2; ++ct) {
        int posl = ct*16 + colr;
        uint2 u;
        u.x = pk2(lk(ha[mt][ct][0]), lk(ha[mt][ct][1]));
        u.y = pk2(lk(ha[mt][ct][2]), lk(ha[mt][ct][3]));
        *(uint2*)(H + posl*128 + (ch2 ^ ((posl&7)<<4))) = u;
      }
    }
    bf16x8 bh[2][2];
    #pragma unroll
    for (int ct = 0; ct < 2; ++ct) {
      int posl = ct*16 + colr;
      #pragma unroll
      for (int k2 = 0; k2 < 2; ++k2)
        bh[ct][k2] = *(const bf16x8*)(H + posl*128 + ((k2*64 + kq*16) ^ ((posl&7)<<4)));
    }

    #pragma unroll
    for (int jj = 0; jj < 2; ++jj) {
      f32x4 h2[2][2];
      #pragma unroll
      for (int mtp = 0; mtp < 2; ++mtp) {
        int r0 = (jj*2 + mtp)*16 + kq*4;
        #pragma unroll
        for (int r = 0; r < 4; ++r) { h2[mtp][0][r] = b_b[r0+r]; h2[mtp][1][r] = b_b[r0+r]; }
      }
      #pragma unroll
      for (int mtp = 0; mtp < 2; ++mtp) {
        int row = (jj*2 + mtp)*16 + colr;
        #pragma unroll
        for (int k2 = 0; k2 < 2; ++k2) {
          bf16x8 w = *(const bf16x8*)(WS + 8192 + row*128 + ((k2*64 + kq*16) ^ ((row&7)<<4)));
          h2[mtp][0] = __builtin_amdgcn_mfma_f32_16x16x32_bf16(w, bh[0][k2], h2[mtp][0], 0, 0, 0);
          h2[mtp][1] = __builtin_amdgcn_mfma_f32_16x16x32_bf16(w, bh[1][k2], h2[mtp][1], 0, 0, 0);
        }
      }
      #pragma unroll
      for (int mtp = 0; mtp < 2; ++mtp) {
        int ch2 = ((jj*2 + mtp)*16 + kq*4) * 2;
        #pragma unroll
        for (int ct = 0; ct < 2; ++ct) {
          int posl = ct*16 + colr;
          uint2 u;
          u.x = pk2(lk(h2[mtp][ct][0]), lk(h2[mtp][ct][1]));
          u.y = pk2(lk(h2[mtp][ct][2]), lk(h2[mtp][ct][3]));
          *(uint2*)(H + posl*128 + (ch2 ^ ((posl&7)<<4))) = u;
        }
      }
      bf16x8 b2[2];
      #pragma unroll
      for (int ct = 0; ct < 2; ++ct) {
        int posl = ct*16 + colr;
        b2[ct] = *(const bf16x8*)(H + posl*128 + ((jj*64 + kq*16) ^ ((posl&7)<<4)));
      }
      #pragma unroll
      for (int mt = 0; mt < 4; ++mt) {
        int row = mt*16 + colr;
        bf16x8 w = *(const bf16x8*)(WS + 16384 + row*128 + ((jj*64 + kq*16) ^ ((row&7)<<4)));
        acc[mt][0] = __builtin_amdgcn_mfma_f32_16x16x32_bf16(w, b2[0], acc[mt][0], 0, 0, 0);
        acc[mt][1] = __builtin_amdgcn_mfma_f32_16x16x32_bf16(w, b2[1], acc[mt][1], 0, 0, 0);
      }
    }

    #pragma unroll
    for (int ct = 0; ct < 2; ++ct) {
      int bn = bn0 + wv*2 + ct;
      #pragma unroll
      for (int mt = 0; mt < 4; ++mt) {
        int ch0 = mt*16 + kq*4;
        uint2 u;
        u.x = pk2(acc[mt][ct][0], acc[mt][ct][1]);
        u.y = pk2(acc[mt][ct][2], acc[mt][ct][3]);
        *(uint2*)(X + ((size_t)(bn*16 + colr))*64 + ch0) = u;
        float m[4];
        #pragma unroll
        for (int r = 0; r < 4; ++r) {
          float v = acc[mt][ct][r];
          v = fmaxf(v, __shfl_xor(v, 1));
          v = fmaxf(v, __shfl_xor(v, 2));
          v = fmaxf(v, __shfl_xor(v, 4));
          v = fmaxf(v, __shfl_xor(v, 8));
          m[r] = v;
        }
        if (colr == 0) {
          uint2 um; um.x = pk2(m[0], m[1]); um.y = pk2(m[2], m[3]);
          *(uint2*)(XM + (size_t)bn*64 + ch0) = um;
        }
      }
    }
  }
}

// ---------------- phase-2 fused MFMA chain, PERSISTENT (8 tiles/block) ----------------
struct P2Shared {
  unsigned short Ws[49152];
  unsigned short Hr[8][2048];
  float outT[128][16];
};

static __device__ __forceinline__ void p2_loadbx(
    bf16x8 (&dst)[2][4], const unsigned short* __restrict__ X,
    const unsigned short* __restrict__ XM, int bn0, int wv, int colr, int kq) {
  #pragma unroll
  for (int ct = 0; ct < 2; ++ct) {
    int bn = bn0 + wv*2 + ct;
    const unsigned short* xr = X + ((size_t)bn*16 + colr)*64 + kq*8;
    dst[ct][0] = *(const bf16x8*)(xr);
    dst[ct][1] = *(const bf16x8*)(xr + 32);
    const unsigned short* mr = XM + (size_t)bn*64 + kq*8;
    dst[ct][2] = *(const bf16x8*)(mr);
    dst[ct][3] = *(const bf16x8*)(mr + 32);
  }
}

__global__ __launch_bounds__(512, 2) void k_p2(
    const unsigned short* __restrict__ X, const unsigned short* __restrict__ XM,
    const unsigned short* __restrict__ wbf,
    const float* __restrict__ sc_b, const float* __restrict__ a_b,
    const float* __restrict__ b_b, const float* __restrict__ c_b,
    float* __restrict__ out) {
  __shared__ __align__(16) P2Shared S;
  const int tid = threadIdx.x;
  const int lane = tid & 63, wv = tid >> 6;
  const int colr = lane & 15, kq = lane >> 4;

  #pragma unroll
  for (int it = 0; it < 12; ++it) {
    int c = it*512 + tid;
    *(uint4*)((char*)S.Ws + c*16) = *(const uint4*)((const char*)wbf + c*16);
  }

  const char* WSC = (const char*)S.Ws;
  const char* WA  = (const char*)(S.Ws + 16384);
  const char* WB  = (const char*)(S.Ws + 24576);
  const char* WC  = (const char*)(S.Ws + 32768);
  char* H = (char*)S.Hr[wv];

#define WF(base, row, K2, ksbyte) \
  (*(const bf16x8*)((base) + (row)*(K2) + ((((ksbyte) + kq*16)) ^ (((row)&7)<<4))))

  bf16x8 bx[2][4], bxn[2][4];
  p2_loadbx(bx, X, XM, blockIdx.x*8*16, wv, colr, kq);
  __syncthreads();

  for (int t = 0; t < 8; ++t) {
    const int bn0 = (blockIdx.x*8 + t) * 16;

    f32x4 acc[8][2];
    #pragma unroll
    for (int mt = 0; mt < 8; ++mt) {
      int r0 = mt*16 + kq*4;
      #pragma unroll
      for (int r = 0; r < 4; ++r) {
        float bia = c_b[r0+r] + sc_b[r0+r];
        acc[mt][0][r] = bia; acc[mt][1][r] = bia;
      }
    }
    #pragma unroll
    for (int mt = 0; mt < 8; ++mt) {
      int row = mt*16 + colr;
      #pragma unroll
      for (int ks = 0; ks < 4; ++ks) {
        bf16x8 w = WF(WSC, row, 256, ks*64);
        acc[mt][0] = __builtin_amdgcn_mfma_f32_16x16x32_bf16(w, bx[0][ks], acc[mt][0], 0, 0, 0);
        acc[mt][1] = __builtin_amdgcn_mfma_f32_16x16x32_bf16(w, bx[1][ks], acc[mt][1], 0, 0, 0);
      }
    }

    f32x4 ha[4][2];
    #pragma unroll
    for (int mt = 0; mt < 4; ++mt) {
      int r0 = mt*16 + kq*4;
      #pragma unroll
      for (int r = 0; r < 4; ++r) { ha[mt][0][r] = a_b[r0+r]; ha[mt][1][r] = a_b[r0+r]; }
    }
    #pragma unroll
    for (int mt = 0; mt < 4; ++mt) {
      int row = mt*16 + colr;
      #pragma unroll
      for (int ks = 0; ks < 4; ++ks) {
        bf16x8 w = WF(WA, row, 256, ks*64);
        ha[mt][0] = __builtin_amdgcn_mfma_f32_16x16x32_bf16(w, bx[0][ks], ha[mt][0], 0, 0, 0);
        ha[mt][1] = __builtin_amdgcn_mfma_f32_16x16x32_bf16(w, bx[1][ks], ha[mt][1], 0, 0, 0);
      }
    }

    {
      int tn = (t < 7) ? (t + 1) : 7;
      p2_loadbx(bxn, X, XM, (blockIdx.x*8 + tn) * 16, wv, colr, kq);
    }

    #pragma unroll
    for (int mt = 0; mt < 4; ++mt) {
      int ch2 = (mt*16 + kq*4) * 2;
      #pragma unroll
      for (int ct = 0; ct < 2; ++ct) {
        int posl = ct*16 + colr;
        uint2 u;
        u.x = pk2(lk(ha[mt][ct][0]), lk(ha[mt][ct][1]));
        u.y = pk2(lk(ha[mt][ct][2]), lk(ha[mt][ct][3]));
        *(uint2*)(H + posl*128 + (ch2 ^ ((posl&7)<<4))) = u;
      }
    }
    bf16x8 bh[2][2];
    #pragma unroll
    for (int ct = 0; ct < 2; ++ct) {
      int posl = ct*16 + colr;
      #pragma unroll
      for (int k2 = 0; k2 < 2; ++k2)
        bh[ct][k2] = *(const bf16x8*)(H + posl*128 + ((k2*64 + kq*16) ^ ((posl&7)<<4)));
    }

    #pragma unroll
    for (int j = 0; j < 4; ++j) {
      f32x4 h2[2][2];
      #pragma unroll
      for (int mtp = 0; mtp < 2; ++mtp) {
        int r0 = (2*j + mtp)*16 + kq*4;
        #pragma unroll
        for (int r = 0; r < 4; ++r) { h2[mtp][0][r] = b_b[r0+r]; h2[mtp][1][r] = b_b[r0+r]; }
      }
      #pragma unroll
      for (int mtp = 0; mtp < 2; ++mtp) {
        int row = (2*j + mtp)*16 + colr;
        #pragma unroll
        for (int k2 = 0; k2 < 2; ++k2) {
          bf16x8 w = WF(WB, row, 128, k2*64);
          h2[mtp][0] = __builtin_amdgcn_mfma_f32_16x16x32_bf16(w, bh[0][k2], h2[mtp][0], 0, 0, 0);
          h2[mtp][1] = __builtin_amdgcn_mfma_f32_16x16x32_bf16(w, bh[1][k2], h2[mtp][1], 0, 0, 0);
        }
      }
      char* PB = H + (j & 1)*2048;
      #pragma unroll
      for (int mtp = 0; mtp < 2; ++mtp) {
        int chp2 = (mtp*16 + kq*4) * 2;
        #pragma unroll
        for (int ct = 0; ct < 2; ++ct) {
          int posl = ct*16 + colr;
          uint2 u;
          u.x = pk2(lk(h2[mtp][ct][0]), lk(h2[mtp][ct][1]));
          u.y = pk2(lk(h2[mtp][ct][2]), lk(h2[mtp][ct][3]));
          *(uint2*)(PB + posl*64 + (chp2 ^ ((posl&3)<<4))) = u;
        }
      }
      bf16x8 b2[2];
      #pragma unroll
      for (int ct = 0; ct < 2; ++ct) {
        int posl = ct*16 + colr;
        b2[ct] = *(const bf16x8*)(PB + posl*64 + ((kq*16) ^ ((posl&3)<<4)));
      }
      #pragma unroll
      for (int mt = 0; mt < 8; ++mt) {
        int row = mt*16 + colr;
        bf16x8 w = WF(WC, row, 256, j*64);
        acc[mt][0] = __builtin_amdgcn_mfma_f32_16x16x32_bf16(w, b2[0], acc[mt][0], 0, 0, 0);
        acc[mt][1] = __builtin_amdgcn_mfma_f32_16x16x32_bf16(w, b2[1], acc[mt][1], 0, 0, 0);
      }
    }

    __syncthreads();
    #pragma unroll
    for (int mt = 0; mt < 8; ++mt) {
      #pragma unroll
      for (int ct = 0; ct < 2; ++ct) {
        #pragma unroll
        for (int r = 0; r < 4; ++r) {
          float v = acc[mt][ct][r];
          v = fmaxf(v, __shfl_xor(v, 1));
          v = fmaxf(v, __shfl_xor(v, 2));
          v = fmaxf(v, __shfl_xor(v, 4));
          v = fmaxf(v, __shfl_xor(v, 8));
          if (colr == 0) S.outT[mt*16 + kq*4 + r][wv*2 + ct] = v;
        }
      }
    }
    __syncthreads();
    {
      int ch = tid >> 2, p = tid & 3;
      int b = bn0 >> 13, n0 = bn0 & (N_-1);
      float4 v4 = *(const float4*)&S.outT[ch][p*4];
      *(float4*)(out + ((size_t)b*128 + ch)*N_ + n0 + p*4) = v4;
    }

    #pragma unroll
    for (int ct = 0; ct < 2; ++ct)
      #pragma unroll
      for (int ks = 0; ks < 4; ++ks)
        bx[ct][ks] = bxn[ct][ks];
  }
#undef WF
}

extern "C" void kernel_launch(void* const* d_in, const int* in_sizes, int n_in,
                              void* d_out, int out_size, void* d_ws, size_t ws_size,
                              hipStream_t stream) {
  const float* xyz     = (const float*)d_in[0];
  const float* p1_sc_w = (const float*)d_in[1];
  const float* p1_sc_b = (const float*)d_in[2];
  const float* p1_a_w  = (const float*)d_in[3];
  const float* p1_a_b  = (const float*)d_in[4];
  const float* p1_b_w  = (const float*)d_in[5];
  const float* p1_b_b  = (const float*)d_in[6];
  const float* p1_c_w  = (const float*)d_in[7];
  const float* p1_c_b  = (const float*)d_in[8];
  const float* p2_sc_w = (const float*)d_in[9];
  const float* p2_sc_b = (const float*)d_in[10];
  const float* p2_a_w  = (const float*)d_in[11];
  const float* p2_a_b  = (const float*)d_in[12];
  const float* p2_b_w  = (const float*)d_in[13];
  const float* p2_b_b  = (const float*)d_in[14];
  const float* p2_c_w  = (const float*)d_in[15];
  const float* p2_c_b  = (const float*)d_in[16];

  if (ws_size < 75497472u) return;  // need ~72 MB scratch
  char* ws = (char*)d_ws;
  float4* pts4        = (float4*)(ws);
  unsigned short* wbf = (unsigned short*)(ws + 524288);
  int* knn            = (int*)(ws + 655360);
  unsigned short* X   = (unsigned short*)(ws + 4194304);
  unsigned short* XM  = (unsigned short*)(ws + 4194304 + 67108864);
  // grid temporaries live inside the X region (dead before k_p1 writes X)
  char* G = ws + 4194304;
  int* hist        = (int*)(G);
  int* ctr         = (int*)(G + 524288);
  int* cid         = (int*)(G + 1048576);
  int* cellStart   = (int*)(G + 1179648);            // 4*(GC+1) ints
  float4* psorted  = (float4*)(G + 1703952);
  int* isorted     = (int*)(G + 2228240);
  float* out = (float*)d_out;

  k_prep<<<dim3(BN_/256), dim3(256), 0, stream>>>(xyz, pts4);
  k_wcvt<<<dim3(240), dim3(256), 0, stream>>>(p2_sc_w, p2_a_w, p2_b_w, p2_c_w,
      p1_a_w, p1_sc_w, p1_b_w, p1_c_w, wbf);
  k_zero<<<dim3(1024), dim3(256), 0, stream>>>(hist, 2*B_*GC);   // hist + ctr (contiguous)
  k_cell<<<dim3(BN_/256), dim3(256), 0, stream>>>(pts4, hist, cid);
  k_scan<<<dim3(B_), dim3(1024), 0, stream>>>(hist, cellStart);
  k_scatter<<<dim3(BN_/256), dim3(256), 0, stream>>>(pts4, cid, cellStart, ctr,
      psorted, isorted);
  k_knng<<<dim3(BN_/4), dim3(256), 0, stream>>>(psorted, isorted,
      cellStart, knn);
  k_p1<<<dim3(512), dim3(512), 0, stream>>>(pts4, knn, wbf,
      p1_a_b, p1_b_b, p1_c_b, p1_sc_b, X, XM);
  k_p2<<<dim3(256), dim3(512), 0, stream>>>(X, XM, wbf,
      p2_sc_b, p2_a_b, p2_b_b, p2_c_b, out);
}

// Round 12
// 422.538 us; speedup vs baseline: 1.3989x; 1.3989x over previous
//
#include <hip/hip_runtime.h>
#include <hip/hip_bf16.h>

#define B_ 4
#define N_ 8192
#define KNN 16
#define BN_ (B_*N_)      // 32768
#define NPOS (BN_*KNN)   // 524288

typedef __attribute__((ext_vector_type(8))) short bf16x8;
typedef __attribute__((ext_vector_type(4))) float f32x4;

static __device__ __forceinline__ unsigned short f2bf(float f) {
  union { float f; unsigned u; } v; v.f = f;
  unsigned r = v.u + 0x7fff + ((v.u >> 16) & 1);
  return (unsigned short)(r >> 16);
}
static __device__ __forceinline__ float lk(float x) { return x >= 0.f ? x : 0.2f*x; }
static __device__ __forceinline__ unsigned pk2(float a, float b) {
  return (unsigned)f2bf(a) | ((unsigned)f2bf(b) << 16);
}

// ---------------- prep: pts4 = (x,y,z,|p|^2) ----------------
__global__ void k_prep(const float* __restrict__ xyz, float4* __restrict__ pts4) {
  int i = blockIdx.x * 256 + threadIdx.x;
  if (i >= BN_) return;
  int b = i >> 13, n = i & (N_-1);
  const float* p = xyz + b*3*N_;
  float x = p[n], y = p[N_+n], z = p[2*N_+n];
  float xx = fmaf(z, z, fmaf(y, y, x*x));
  pts4[i] = make_float4(x, y, z, xx);
}

// ------- convert ALL weights to bf16, PRE-SWIZZLED LDS images -------
__global__ void k_wcvt(const float* __restrict__ w_sc, const float* __restrict__ w_a,
                       const float* __restrict__ w_b, const float* __restrict__ w_c,
                       const float* __restrict__ p1a, const float* __restrict__ p1sc,
                       const float* __restrict__ p1b, const float* __restrict__ p1c,
                       unsigned short* __restrict__ out) {
  int i = blockIdx.x*256 + threadIdx.x;
  if (i >= 61440) return;
  if (i < 49152) {
    int x = i*2;                            // byte offset in p2 image
    const float* w; int base, K2;
    if (x < 32768)      { w = w_sc; base = 0;     K2 = 256; }
    else if (x < 49152) { w = w_a;  base = 32768; K2 = 256; }
    else if (x < 65536) { w = w_b;  base = 49152; K2 = 128; }
    else                { w = w_c;  base = 65536; K2 = 256; }
    int off = x - base;
    int row = off / K2;
    int colb = (off & (K2-1)) ^ ((row & 7) << 4);
    int k = colb >> 1;
    out[i] = f2bf(w[row*(K2 >> 1) + k]);
  } else {
    int e = i - 49152;                      // 0..12287
    float val; int byteoff;
    if (e < 2048) {               // Wa 64x32 (64B rows)
      int row = e >> 5, k = e & 31;
      val = (k < 10) ? p1a[row*10 + k] : 0.f;
      byteoff = row*64 + ((2*k) ^ ((row & 3) << 4));
    } else if (e < 4096) {        // Wsc 64x32
      int le = e - 2048, row = le >> 5, k = le & 31;
      val = (k < 10) ? p1sc[row*10 + k] : 0.f;
      byteoff = 4096 + row*64 + ((2*k) ^ ((row & 3) << 4));
    } else if (e < 8192) {        // Wb 64x64 (128B rows)
      int le = e - 4096, row = le >> 6, k = le & 63;
      val = p1b[row*64 + k];
      byteoff = 8192 + row*128 + ((2*k) ^ ((row & 7) << 4));
    } else {                      // Wc 64x64
      int le = e - 8192, row = le >> 6, k = le & 63;
      val = p1c[row*64 + k];
      byteoff = 16384 + row*128 + ((2*k) ^ ((row & 7) << 4));
    }
    out[49152 + (byteoff >> 1)] = f2bf(val);
  }
}

// ---------------- KNN (round-7 proven structure, U=8 batching) ----------------
// u64 key = (f32bits(d2) << 32) | idx -> ascending u64 == lexicographic (d2, idx).
static __device__ __forceinline__ unsigned long long bitonic64(
    unsigned long long key, int lane) {
  #pragma unroll
  for (int size = 2; size <= 64; size <<= 1) {
    #pragma unroll
    for (int stride = size >> 1; stride >= 1; stride >>= 1) {
      unsigned long long ok = __shfl_xor((long long)key, stride);
      bool up = ((lane & size) == 0);
      bool keepmin = (((lane & stride) == 0) == up);
      bool oless = ok < key;
      if (oless == keepmin) key = ok;
    }
  }
  return key;
}

template<int U>
static __device__ __forceinline__ void scan_groups(
    const float4* __restrict__ cand, int itbase, int ch,
    float4 me, int lane,
    unsigned long long* __restrict__ bw,
    unsigned long long& topk, float& rhs, int& cnt) {
  // phase 1: U independent loads + screen values, NO control flow between them
  float s[U]; int cid[U];
  #pragma unroll
  for (int u = 0; u < U; ++u) {
    int ci = (itbase + u)*64 + lane;
    float4 c = cand[ci];
    float dot = fmaf(me.z, c.z, fmaf(me.y, c.y, me.x*c.x));
    s[u] = fmaf(-2.0f, dot, c.w);          // d2 = me.w + s
    cid[u] = ch*2048 + ci;
  }
  // phase 2: ballot checks; appends rare, compactions rarer
  #pragma unroll
  for (int u = 0; u < U; ++u) {
    unsigned long long m = __ballot(s[u] < rhs);
    if (m) {
      int prefix = __builtin_amdgcn_mbcnt_hi((unsigned)(m >> 32),
                    __builtin_amdgcn_mbcnt_lo((unsigned)m, 0));
      if (s[u] < rhs) {
        float d2 = me.w + s[u];
        bw[cnt + prefix] =
          ((unsigned long long)__float_as_uint(d2) << 32) | (unsigned)cid[u];
      }
      cnt += __popcll(m);
      if (cnt >= 48) {      // keep invariant: cnt<48 before any append batch (buf 112)
        int base = 0;
        while (cnt > 0) {
          int c2 = cnt > 48 ? 48 : cnt;
          unsigned long long e = (lane < 16) ? topk
            : ((lane - 16) < c2 ? bw[base + lane - 16] : ~0ull);
          topk = bitonic64(e, lane);
          base += c2; cnt -= c2;
        }
        unsigned long long k15 = __shfl((long long)topk, 15);
        rhs = __uint_as_float((unsigned)(k15 >> 32)) - me.w;
      }
    }
  }
}

__global__ __launch_bounds__(512) void k_knn(const float4* __restrict__ pts4,
                                             int* __restrict__ knn) {
  __shared__ float4 cand[2048];
  __shared__ unsigned long long buf[8][112];
  const int lane = threadIdx.x & 63;
  const int wv   = threadIdx.x >> 6;
  const int q = blockIdx.x * 8 + wv;
  const int b = q >> 13;
  const int n = q & (N_-1);
  const float4* __restrict__ P = pts4 + (b << 13);
  float4 me = P[n];

  unsigned long long topk = ~0ull;   // lanes 0..15: sorted top-16 keys
  float rhs = __builtin_inff();      // worst - me.w
  int cnt = 0;
  unsigned long long* __restrict__ bw = buf[wv];

  for (int ch = 0; ch < 4; ++ch) {
    __syncthreads();
    #pragma unroll
    for (int t = 0; t < 4; ++t)
      cand[t*512 + threadIdx.x] = P[ch*2048 + t*512 + threadIdx.x];
    __syncthreads();

    if (ch == 0) {
      // warm start: exact top-16 of candidates 0..63
      float4 c = cand[lane];
      float dot = fmaf(me.z, c.z, fmaf(me.y, c.y, me.x*c.x));
      float d2 = (me.w + c.w) - 2.0f*dot;
      unsigned long long key =
        ((unsigned long long)__float_as_uint(d2) << 32) | (unsigned)lane;
      topk = bitonic64(key, lane);
      unsigned long long k15 = __shfl((long long)topk, 15);
      rhs = __uint_as_float((unsigned)(k15 >> 32)) - me.w;
      scan_groups<3>(cand, 1, 0, me, lane, bw, topk, rhs, cnt);
      #pragma unroll 1
      for (int it = 4; it < 28; it += 8)
        scan_groups<8>(cand, it, 0, me, lane, bw, topk, rhs, cnt);
      scan_groups<4>(cand, 28, 0, me, lane, bw, topk, rhs, cnt);
    } else {
      #pragma unroll 1
      for (int it = 0; it < 32; it += 8)
        scan_groups<8>(cand, it, ch, me, lane, bw, topk, rhs, cnt);
    }
  }
  // final drain
  {
    int base = 0;
    while (cnt > 0) {
      int c2 = cnt > 48 ? 48 : cnt;
      unsigned long long e = (lane < 16) ? topk
        : ((lane - 16) < c2 ? bw[base + lane - 16] : ~0ull);
      topk = bitonic64(e, lane);
      base += c2; cnt -= c2;
    }
  }
  if (lane < 16) knn[(q << 4) + lane] = (int)(unsigned)(topk & 0xffffffffu);
}

// ---------------- phase-1 conv-res on MFMA, PERSISTENT (4 tiles/block) ----------------
__global__ __launch_bounds__(512, 4) void k_p1(
    const float4* __restrict__ pts4, const int* __restrict__ knn,
    const unsigned short* __restrict__ wbf,
    const float* __restrict__ a_b, const float* __restrict__ b_b,
    const float* __restrict__ c_b, const float* __restrict__ sc_b,
    unsigned short* __restrict__ X, unsigned short* __restrict__ XM) {
  __shared__ __align__(16) unsigned short Ws1[12288];  // 24 KB swizzled weights
  __shared__ __align__(16) unsigned short Fs[8192];    // 16 KB features
  __shared__ __align__(16) unsigned short Hr[16384];   // 32 KB wave H regions
  const int tid = threadIdx.x;
  const int lane = tid & 63, wv = tid >> 6;
  const int colr = lane & 15, kq = lane >> 4;

  #pragma unroll
  for (int j = 0; j < 3; ++j) {
    int c = j*512 + tid;
    ((uint4*)Ws1)[c] = ((const uint4*)(wbf + 49152))[c];
  }
  const char* WS = (const char*)Ws1;
  char* H = (char*)Hr + wv*4096;

  for (int tile = 0; tile < 4; ++tile) {
    const int bn0 = (blockIdx.x*4 + tile) * 16;
    __syncthreads();
    if (tid < 256) {
      int bnl = tid >> 4, kk = tid & 15;
      int bn = bn0 + bnl;
      int b = bn >> 13;
      float4 cp = pts4[bn];
      int nid = knn[bn*16 + kk];
      float4 np = pts4[(b << 13) + nid];
      float rx = np.x - cp.x, ry = np.y - cp.y, rz = np.z - cp.z;
      float dist = sqrtf(fmaf(rz, rz, fmaf(ry, ry, rx*rx)) + 1e-12f);
      unsigned short row[32];
      row[0]=f2bf(cp.x); row[1]=f2bf(cp.y); row[2]=f2bf(cp.z);
      row[3]=f2bf(np.x); row[4]=f2bf(np.y); row[5]=f2bf(np.z);
      row[6]=f2bf(rx);   row[7]=f2bf(ry);   row[8]=f2bf(rz);   row[9]=f2bf(dist);
      #pragma unroll
      for (int j = 10; j < 32; ++j) row[j] = 0;
      int wvp = tid >> 5, posl = tid & 31;
      char* dst = (char*)Fs + wvp*2048 + posl*64;
      #pragma unroll
      for (int c = 0; c < 4; ++c)
        *(uint4*)(dst + ((c*16) ^ ((posl&3)<<4))) = *(const uint4*)(row + c*8);
    }
    __syncthreads();

    bf16x8 bfr[2];
    #pragma unroll
    for (int ct = 0; ct < 2; ++ct) {
      int posl = ct*16 + colr;
      bfr[ct] = *(const bf16x8*)((const char*)Fs + wv*2048 + posl*64 + ((kq*16) ^ ((posl&3)<<4)));
    }

    f32x4 acc[4][2];
    #pragma unroll
    for (int mt = 0; mt < 4; ++mt) {
      int r0 = mt*16 + kq*4;
      #pragma unroll
      for (int r = 0; r < 4; ++r) {
        float bia = c_b[r0+r] + sc_b[r0+r];
        acc[mt][0][r] = bia; acc[mt][1][r] = bia;
      }
    }
    #pragma unroll
    for (int mt = 0; mt < 4; ++mt) {
      int row = mt*16 + colr;
      bf16x8 w = *(const bf16x8*)(WS + 4096 + row*64 + ((kq*16) ^ ((row&3)<<4)));
      acc[mt][0] = __builtin_amdgcn_mfma_f32_16x16x32_bf16(w, bfr[0], acc[mt][0], 0, 0, 0);
      acc[mt][1] = __builtin_amdgcn_mfma_f32_16x16x32_bf16(w, bfr[1], acc[mt][1], 0, 0, 0);
    }

    f32x4 ha[4][2];
    #pragma unroll
    for (int mt = 0; mt < 4; ++mt) {
      int r0 = mt*16 + kq*4;
      #pragma unroll
      for (int r = 0; r < 4; ++r) { ha[mt][0][r] = a_b[r0+r]; ha[mt][1][r] = a_b[r0+r]; }
    }
    #pragma unroll
    for (int mt = 0; mt < 4; ++mt) {
      int row = mt*16 + colr;
      bf16x8 w = *(const bf16x8*)(WS + row*64 + ((kq*16) ^ ((row&3)<<4)));
      ha[mt][0] = __builtin_amdgcn_mfma_f32_16x16x32_bf16(w, bfr[0], ha[mt][0], 0, 0, 0);
      ha[mt][1] = __builtin_amdgcn_mfma_f32_16x16x32_bf16(w, bfr[1], ha[mt][1], 0, 0, 0);
    }

    #pragma unroll
    for (int mt = 0; mt < 4; ++mt) {
      int ch2 = (mt*16 + kq*4) * 2;
      #pragma unroll
      for (int ct = 0; ct < 2; ++ct) {
        int posl = ct*16 + colr;
        uint2 u;
        u.x = pk2(lk(ha[mt][ct][0]), lk(ha[mt][ct][1]));
        u.y = pk2(lk(ha[mt][ct][2]), lk(ha[mt][ct][3]));
        *(uint2*)(H + posl*128 + (ch2 ^ ((posl&7)<<4))) = u;
      }
    }
    bf16x8 bh[2][2];
    #pragma unroll
    for (int ct = 0; ct < 2; ++ct) {
      int posl = ct*16 + colr;
      #pragma unroll
      for (int k2 = 0; k2 < 2; ++k2)
        bh[ct][k2] = *(const bf16x8*)(H + posl*128 + ((k2*64 + kq*16) ^ ((posl&7)<<4)));
    }

    #pragma unroll
    for (int jj = 0; jj < 2; ++jj) {
      f32x4 h2[2][2];
      #pragma unroll
      for (int mtp = 0; mtp < 2; ++mtp) {
        int r0 = (jj*2 + mtp)*16 + kq*4;
        #pragma unroll
        for (int r = 0; r < 4; ++r) { h2[mtp][0][r] = b_b[r0+r]; h2[mtp][1][r] = b_b[r0+r]; }
      }
      #pragma unroll
      for (int mtp = 0; mtp < 2; ++mtp) {
        int row = (jj*2 + mtp)*16 + colr;
        #pragma unroll
        for (int k2 = 0; k2 < 2; ++k2) {
          bf16x8 w = *(const bf16x8*)(WS + 8192 + row*128 + ((k2*64 + kq*16) ^ ((row&7)<<4)));
          h2[mtp][0] = __builtin_amdgcn_mfma_f32_16x16x32_bf16(w, bh[0][k2], h2[mtp][0], 0, 0, 0);
          h2[mtp][1] = __builtin_amdgcn_mfma_f32_16x16x32_bf16(w, bh[1][k2], h2[mtp][1], 0, 0, 0);
        }
      }
      #pragma unroll
      for (int mtp = 0; mtp < 2; ++mtp) {
        int ch2 = ((jj*2 + mtp)*16 + kq*4) * 2;
        #pragma unroll
        for (int ct = 0; ct < 2; ++ct) {
          int posl = ct*16 + colr;
          uint2 u;
          u.x = pk2(lk(h2[mtp][ct][0]), lk(h2[mtp][ct][1]));
          u.y = pk2(lk(h2[mtp][ct][2]), lk(h2[mtp][ct][3]));
          *(uint2*)(H + posl*128 + (ch2 ^ ((posl&7)<<4))) = u;
        }
      }
      bf16x8 b2[2];
      #pragma unroll
      for (int ct = 0; ct < 2; ++ct) {
        int posl = ct*16 + colr;
        b2[ct] = *(const bf16x8*)(H + posl*128 + ((jj*64 + kq*16) ^ ((posl&7)<<4)));
      }
      #pragma unroll
      for (int mt = 0; mt < 4; ++mt) {
        int row = mt*16 + colr;
        bf16x8 w = *(const bf16x8*)(WS + 16384 + row*128 + ((jj*64 + kq*16) ^ ((row&7)<<4)));
        acc[mt][0] = __builtin_amdgcn_mfma_f32_16x16x32_bf16(w, b2[0], acc[mt][0], 0, 0, 0);
        acc[mt][1] = __builtin_amdgcn_mfma_f32_16x16x32_bf16(w, b2[1], acc[mt][1], 0, 0, 0);
      }
    }

    #pragma unroll
    for (int ct = 0; ct < 2; ++ct) {
      int bn = bn0 + wv*2 + ct;
      #pragma unroll
      for (int mt = 0; mt < 4; ++mt) {
        int ch0 = mt*16 + kq*4;
        uint2 u;
        u.x = pk2(acc[mt][ct][0], acc[mt][ct][1]);
        u.y = pk2(acc[mt][ct][2], acc[mt][ct][3]);
        *(uint2*)(X + ((size_t)(bn*16 + colr))*64 + ch0) = u;
        float m[4];
        #pragma unroll
        for (int r = 0; r < 4; ++r) {
          float v = acc[mt][ct][r];
          v = fmaxf(v, __shfl_xor(v, 1));
          v = fmaxf(v, __shfl_xor(v, 2));
          v = fmaxf(v, __shfl_xor(v, 4));
          v = fmaxf(v, __shfl_xor(v, 8));
          m[r] = v;
        }
        if (colr == 0) {
          uint2 um; um.x = pk2(m[0], m[1]); um.y = pk2(m[2], m[3]);
          *(uint2*)(XM + (size_t)bn*64 + ch0) = um;
        }
      }
    }
  }
}

// ---------------- phase-2 fused MFMA chain, PERSISTENT (8 tiles/block) ----------------
struct P2Shared {
  unsigned short Ws[49152];
  unsigned short Hr[8][2048];
  float outT[128][16];
};

static __device__ __forceinline__ void p2_loadbx(
    bf16x8 (&dst)[2][4], const unsigned short* __restrict__ X,
    const unsigned short* __restrict__ XM, int bn0, int wv, int colr, int kq) {
  #pragma unroll
  for (int ct = 0; ct < 2; ++ct) {
    int bn = bn0 + wv*2 + ct;
    const unsigned short* xr = X + ((size_t)bn*16 + colr)*64 + kq*8;
    dst[ct][0] = *(const bf16x8*)(xr);
    dst[ct][1] = *(const bf16x8*)(xr + 32);
    const unsigned short* mr = XM + (size_t)bn*64 + kq*8;
    dst[ct][2] = *(const bf16x8*)(mr);
    dst[ct][3] = *(const bf16x8*)(mr + 32);
  }
}

__global__ __launch_bounds__(512, 2) void k_p2(
    const unsigned short* __restrict__ X, const unsigned short* __restrict__ XM,
    const unsigned short* __restrict__ wbf,
    const float* __restrict__ sc_b, const float* __restrict__ a_b,
    const float* __restrict__ b_b, const float* __restrict__ c_b,
    float* __restrict__ out) {
  __shared__ __align__(16) P2Shared S;
  const int tid = threadIdx.x;
  const int lane = tid & 63, wv = tid >> 6;
  const int colr = lane & 15, kq = lane >> 4;

  #pragma unroll
  for (int it = 0; it < 12; ++it) {
    int c = it*512 + tid;
    *(uint4*)((char*)S.Ws + c*16) = *(const uint4*)((const char*)wbf + c*16);
  }

  const char* WSC = (const char*)S.Ws;
  const char* WA  = (const char*)(S.Ws + 16384);
  const char* WB  = (const char*)(S.Ws + 24576);
  const char* WC  = (const char*)(S.Ws + 32768);
  char* H = (char*)S.Hr[wv];

#define WF(base, row, K2, ksbyte) \
  (*(const bf16x8*)((base) + (row)*(K2) + ((((ksbyte) + kq*16)) ^ (((row)&7)<<4))))

  bf16x8 bx[2][4], bxn[2][4];
  p2_loadbx(bx, X, XM, blockIdx.x*8*16, wv, colr, kq);
  __syncthreads();

  for (int t = 0; t < 8; ++t) {
    const int bn0 = (blockIdx.x*8 + t) * 16;

    f32x4 acc[8][2];
    #pragma unroll
    for (int mt = 0; mt < 8; ++mt) {
      int r0 = mt*16 + kq*4;
      #pragma unroll
      for (int r = 0; r < 4; ++r) {
        float bia = c_b[r0+r] + sc_b[r0+r];
        acc[mt][0][r] = bia; acc[mt][1][r] = bia;
      }
    }
    #pragma unroll
    for (int mt = 0; mt < 8; ++mt) {
      int row = mt*16 + colr;
      #pragma unroll
      for (int ks = 0; ks < 4; ++ks) {
        bf16x8 w = WF(WSC, row, 256, ks*64);
        acc[mt][0] = __builtin_amdgcn_mfma_f32_16x16x32_bf16(w, bx[0][ks], acc[mt][0], 0, 0, 0);
        acc[mt][1] = __builtin_amdgcn_mfma_f32_16x16x32_bf16(w, bx[1][ks], acc[mt][1], 0, 0, 0);
      }
    }

    f32x4 ha[4][2];
    #pragma unroll
    for (int mt = 0; mt < 4; ++mt) {
      int r0 = mt*16 + kq*4;
      #pragma unroll
      for (int r = 0; r < 4; ++r) { ha[mt][0][r] = a_b[r0+r]; ha[mt][1][r] = a_b[r0+r]; }
    }
    #pragma unroll
    for (int mt = 0; mt < 4; ++mt) {
      int row = mt*16 + colr;
      #pragma unroll
      for (int ks = 0; ks < 4; ++ks) {
        bf16x8 w = WF(WA, row, 256, ks*64);
        ha[mt][0] = __builtin_amdgcn_mfma_f32_16x16x32_bf16(w, bx[0][ks], ha[mt][0], 0, 0, 0);
        ha[mt][1] = __builtin_amdgcn_mfma_f32_16x16x32_bf16(w, bx[1][ks], ha[mt][1], 0, 0, 0);
      }
    }

    {
      int tn = (t < 7) ? (t + 1) : 7;
      p2_loadbx(bxn, X, XM, (blockIdx.x*8 + tn) * 16, wv, colr, kq);
    }

    #pragma unroll
    for (int mt = 0; mt < 4; ++mt) {
      int ch2 = (mt*16 + kq*4) * 2;
      #pragma unroll
      for (int ct = 0; ct < 2; ++ct) {
        int posl = ct*16 + colr;
        uint2 u;
        u.x = pk2(lk(ha[mt][ct][0]), lk(ha[mt][ct][1]));
        u.y = pk2(lk(ha[mt][ct][2]), lk(ha[mt][ct][3]));
        *(uint2*)(H + posl*128 + (ch2 ^ ((posl&7)<<4))) = u;
      }
    }
    bf16x8 bh[2][2];
    #pragma unroll
    for (int ct = 0; ct < 2; ++ct) {
      int posl = ct*16 + colr;
      #pragma unroll
      for (int k2 = 0; k2 < 2; ++k2)
        bh[ct][k2] = *(const bf16x8*)(H + posl*128 + ((k2*64 + kq*16) ^ ((posl&7)<<4)));
    }

    #pragma unroll
    for (int j = 0; j < 4; ++j) {
      f32x4 h2[2][2];
      #pragma unroll
      for (int mtp = 0; mtp < 2; ++mtp) {
        int r0 = (2*j + mtp)*16 + kq*4;
        #pragma unroll
        for (int r = 0; r < 4; ++r) { h2[mtp][0][r] = b_b[r0+r]; h2[mtp][1][r] = b_b[r0+r]; }
      }
      #pragma unroll
      for (int mtp = 0; mtp < 2; ++mtp) {
        int row = (2*j + mtp)*16 + colr;
        #pragma unroll
        for (int k2 = 0; k2 < 2; ++k2) {
          bf16x8 w = WF(WB, row, 128, k2*64);
          h2[mtp][0] = __builtin_amdgcn_mfma_f32_16x16x32_bf16(w, bh[0][k2], h2[mtp][0], 0, 0, 0);
          h2[mtp][1] = __builtin_amdgcn_mfma_f32_16x16x32_bf16(w, bh[1][k2], h2[mtp][1], 0, 0, 0);
        }
      }
      char* PB = H + (j & 1)*2048;
      #pragma unroll
      for (int mtp = 0; mtp < 2; ++mtp) {
        int chp2 = (mtp*16 + kq*4) * 2;
        #pragma unroll
        for (int ct = 0; ct < 2; ++ct) {
          int posl = ct*16 + colr;
          uint2 u;
          u.x = pk2(lk(h2[mtp][ct][0]), lk(h2[mtp][ct][1]));
          u.y = pk2(lk(h2[mtp][ct][2]), lk(h2[mtp][ct][3]));
          *(uint2*)(PB + posl*64 + (chp2 ^ ((posl&3)<<4))) = u;
        }
      }
      bf16x8 b2[2];
      #pragma unroll
      for (int ct = 0; ct < 2; ++ct) {
        int posl = ct*16 + colr;
        b2[ct] = *(const bf16x8*)(PB + posl*64 + ((kq*16) ^ ((posl&3)<<4)));
      }
      #pragma unroll
      for (int mt = 0; mt < 8; ++mt) {
        int row = mt*16 + colr;
        bf16x8 w = WF(WC, row, 256, j*64);
        acc[mt][0] = __builtin_amdgcn_mfma_f32_16x16x32_bf16(w, b2[0], acc[mt][0], 0, 0, 0);
        acc[mt][1] = __builtin_amdgcn_mfma_f32_16x16x32_bf16(w, b2[1], acc[mt][1], 0, 0, 0);
      }
    }

    __syncthreads();
    #pragma unroll
    for (int mt = 0; mt < 8; ++mt) {
      #pragma unroll
      for (int ct = 0; ct < 2; ++ct) {
        #pragma unroll
        for (int r = 0; r < 4; ++r) {
          float v = acc[mt][ct][r];
          v = fmaxf(v, __shfl_xor(v, 1));
          v = fmaxf(v, __shfl_xor(v, 2));
          v = fmaxf(v, __shfl_xor(v, 4));
          v = fmaxf(v, __shfl_xor(v, 8));
          if (colr == 0) S.outT[mt*16 + kq*4 + r][wv*2 + ct] = v;
        }
      }
    }
    __syncthreads();
    {
      int ch = tid >> 2, p = tid & 3;
      int b = bn0 >> 13, n0 = bn0 & (N_-1);
      float4 v4 = *(const float4*)&S.outT[ch][p*4];
      *(float4*)(out + ((size_t)b*128 + ch)*N_ + n0 + p*4) = v4;
    }

    #pragma unroll
    for (int ct = 0; ct < 2; ++ct)
      #pragma unroll
      for (int ks = 0; ks < 4; ++ks)
        bx[ct][ks] = bxn[ct][ks];
  }
#undef WF
}

extern "C" void kernel_launch(void* const* d_in, const int* in_sizes, int n_in,
                              void* d_out, int out_size, void* d_ws, size_t ws_size,
                              hipStream_t stream) {
  const float* xyz     = (const float*)d_in[0];
  const float* p1_sc_w = (const float*)d_in[1];
  const float* p1_sc_b = (const float*)d_in[2];
  const float* p1_a_w  = (const float*)d_in[3];
  const float* p1_a_b  = (const float*)d_in[4];
  const float* p1_b_w  = (const float*)d_in[5];
  const float* p1_b_b  = (const float*)d_in[6];
  const float* p1_c_w  = (const float*)d_in[7];
  const float* p1_c_b  = (const float*)d_in[8];
  const float* p2_sc_w = (const float*)d_in[9];
  const float* p2_sc_b = (const float*)d_in[10];
  const float* p2_a_w  = (const float*)d_in[11];
  const float* p2_a_b  = (const float*)d_in[12];
  const float* p2_b_w  = (const float*)d_in[13];
  const float* p2_b_b  = (const float*)d_in[14];
  const float* p2_c_w  = (const float*)d_in[15];
  const float* p2_c_b  = (const float*)d_in[16];

  if (ws_size < 75497472u) return;  // need ~72 MB scratch
  char* ws = (char*)d_ws;
  float4* pts4        = (float4*)(ws);
  unsigned short* wbf = (unsigned short*)(ws + 524288);
  int* knn            = (int*)(ws + 655360);
  unsigned short* X   = (unsigned short*)(ws + 4194304);
  unsigned short* XM  = (unsigned short*)(ws + 4194304 + 67108864);
  float* out = (float*)d_out;

  k_prep<<<dim3(BN_/256), dim3(256), 0, stream>>>(xyz, pts4);
  k_wcvt<<<dim3(240), dim3(256), 0, stream>>>(p2_sc_w, p2_a_w, p2_b_w, p2_c_w,
      p1_a_w, p1_sc_w, p1_b_w, p1_c_w, wbf);
  k_knn<<<dim3(BN_/8), dim3(512), 0, stream>>>(pts4, knn);
  k_p1<<<dim3(512), dim3(512), 0, stream>>>(pts4, knn, wbf,
      p1_a_b, p1_b_b, p1_c_b, p1_sc_b, X, XM);
  k_p2<<<dim3(256), dim3(512), 0, stream>>>(X, XM, wbf,
      p2_sc_b, p2_a_b, p2_b_b, p2_c_b, out);
}

// Round 13
// 378.144 us; speedup vs baseline: 1.5632x; 1.1174x over previous
//
#include <hip/hip_runtime.h>
#include <hip/hip_bf16.h>

#define B_ 4
#define N_ 8192
#define KNN 16
#define BN_ (B_*N_)      // 32768
#define NPOS (BN_*KNN)   // 524288

typedef __attribute__((ext_vector_type(8))) short bf16x8;
typedef __attribute__((ext_vector_type(4))) float f32x4;

static __device__ __forceinline__ unsigned short f2bf(float f) {
  union { float f; unsigned u; } v; v.f = f;
  unsigned r = v.u + 0x7fff + ((v.u >> 16) & 1);
  return (unsigned short)(r >> 16);
}
static __device__ __forceinline__ float lk(float x) { return x >= 0.f ? x : 0.2f*x; }
static __device__ __forceinline__ unsigned pk2(float a, float b) {
  return (unsigned)f2bf(a) | ((unsigned)f2bf(b) << 16);
}

// ---------------- prep: pts4 = (x,y,z,|p|^2) ----------------
__global__ void k_prep(const float* __restrict__ xyz, float4* __restrict__ pts4) {
  int i = blockIdx.x * 256 + threadIdx.x;
  if (i >= BN_) return;
  int b = i >> 13, n = i & (N_-1);
  const float* p = xyz + b*3*N_;
  float x = p[n], y = p[N_+n], z = p[2*N_+n];
  float xx = fmaf(z, z, fmaf(y, y, x*x));
  pts4[i] = make_float4(x, y, z, xx);
}

// ------- convert ALL weights to bf16, PRE-SWIZZLED LDS images -------
__global__ void k_wcvt(const float* __restrict__ w_sc, const float* __restrict__ w_a,
                       const float* __restrict__ w_b, const float* __restrict__ w_c,
                       const float* __restrict__ p1a, const float* __restrict__ p1sc,
                       const float* __restrict__ p1b, const float* __restrict__ p1c,
                       unsigned short* __restrict__ out) {
  int i = blockIdx.x*256 + threadIdx.x;
  if (i >= 61440) return;
  if (i < 49152) {
    int x = i*2;                            // byte offset in p2 image
    const float* w; int base, K2;
    if (x < 32768)      { w = w_sc; base = 0;     K2 = 256; }
    else if (x < 49152) { w = w_a;  base = 32768; K2 = 256; }
    else if (x < 65536) { w = w_b;  base = 49152; K2 = 128; }
    else                { w = w_c;  base = 65536; K2 = 256; }
    int off = x - base;
    int row = off / K2;
    int colb = (off & (K2-1)) ^ ((row & 7) << 4);
    int k = colb >> 1;
    out[i] = f2bf(w[row*(K2 >> 1) + k]);
  } else {
    int e = i - 49152;                      // 0..12287
    float val; int byteoff;
    if (e < 2048) {               // Wa 64x32 (64B rows)
      int row = e >> 5, k = e & 31;
      val = (k < 10) ? p1a[row*10 + k] : 0.f;
      byteoff = row*64 + ((2*k) ^ ((row & 3) << 4));
    } else if (e < 4096) {        // Wsc 64x32
      int le = e - 2048, row = le >> 5, k = le & 31;
      val = (k < 10) ? p1sc[row*10 + k] : 0.f;
      byteoff = 4096 + row*64 + ((2*k) ^ ((row & 3) << 4));
    } else if (e < 8192) {        // Wb 64x64 (128B rows)
      int le = e - 4096, row = le >> 6, k = le & 63;
      val = p1b[row*64 + k];
      byteoff = 8192 + row*128 + ((2*k) ^ ((row & 7) << 4));
    } else {                      // Wc 64x64
      int le = e - 8192, row = le >> 6, k = le & 63;
      val = p1c[row*64 + k];
      byteoff = 16384 + row*128 + ((2*k) ^ ((row & 7) << 4));
    }
    out[49152 + (byteoff >> 1)] = f2bf(val);
  }
}

// ---------------- KNN (round-7 proven: U=4 batched scan + ballot-append) ----------------
// u64 key = (f32bits(d2) << 32) | idx -> ascending u64 == lexicographic (d2, idx).
static __device__ __forceinline__ unsigned long long bitonic64(
    unsigned long long key, int lane) {
  #pragma unroll
  for (int size = 2; size <= 64; size <<= 1) {
    #pragma unroll
    for (int stride = size >> 1; stride >= 1; stride >>= 1) {
      unsigned long long ok = __shfl_xor((long long)key, stride);
      bool up = ((lane & size) == 0);
      bool keepmin = (((lane & stride) == 0) == up);
      bool oless = ok < key;
      if (oless == keepmin) key = ok;
    }
  }
  return key;
}

template<int U>
static __device__ __forceinline__ void scan_groups(
    const float4* __restrict__ cand, int itbase, int ch,
    float4 me, int lane,
    unsigned long long* __restrict__ bw,
    unsigned long long& topk, float& rhs, int& cnt) {
  // phase 1: U independent loads + screen values, NO control flow between them
  float s[U]; int cid[U];
  #pragma unroll
  for (int u = 0; u < U; ++u) {
    int ci = (itbase + u)*64 + lane;
    float4 c = cand[ci];
    float dot = fmaf(me.z, c.z, fmaf(me.y, c.y, me.x*c.x));
    s[u] = fmaf(-2.0f, dot, c.w);          // d2 = me.w + s
    cid[u] = ch*2048 + ci;
  }
  // phase 2: ballot checks; appends rare, compactions rarer
  #pragma unroll
  for (int u = 0; u < U; ++u) {
    unsigned long long m = __ballot(s[u] < rhs);
    if (m) {
      int prefix = __builtin_amdgcn_mbcnt_hi((unsigned)(m >> 32),
                    __builtin_amdgcn_mbcnt_lo((unsigned)m, 0));
      if (s[u] < rhs) {
        float d2 = me.w + s[u];
        bw[cnt + prefix] =
          ((unsigned long long)__float_as_uint(d2) << 32) | (unsigned)cid[u];
      }
      cnt += __popcll(m);
      if (cnt >= 48) {      // keep invariant: cnt<48 before any append batch (buf 112)
        int base = 0;
        while (cnt > 0) {
          int c2 = cnt > 48 ? 48 : cnt;
          unsigned long long e = (lane < 16) ? topk
            : ((lane - 16) < c2 ? bw[base + lane - 16] : ~0ull);
          topk = bitonic64(e, lane);
          base += c2; cnt -= c2;
        }
        unsigned long long k15 = __shfl((long long)topk, 15);
        rhs = __uint_as_float((unsigned)(k15 >> 32)) - me.w;
      }
    }
  }
}

__global__ __launch_bounds__(512) void k_knn(const float4* __restrict__ pts4,
                                             int* __restrict__ knn) {
  __shared__ float4 cand[2048];
  __shared__ unsigned long long buf[8][112];
  const int lane = threadIdx.x & 63;
  const int wv   = threadIdx.x >> 6;
  const int q = blockIdx.x * 8 + wv;
  const int b = q >> 13;
  const int n = q & (N_-1);
  const float4* __restrict__ P = pts4 + (b << 13);
  float4 me = P[n];

  unsigned long long topk = ~0ull;   // lanes 0..15: sorted top-16 keys
  float rhs = __builtin_inff();      // worst - me.w
  int cnt = 0;
  unsigned long long* __restrict__ bw = buf[wv];

  for (int ch = 0; ch < 4; ++ch) {
    __syncthreads();
    #pragma unroll
    for (int t = 0; t < 4; ++t)
      cand[t*512 + threadIdx.x] = P[ch*2048 + t*512 + threadIdx.x];
    __syncthreads();

    if (ch == 0) {
      // warm start: exact top-16 of candidates 0..63
      float4 c = cand[lane];
      float dot = fmaf(me.z, c.z, fmaf(me.y, c.y, me.x*c.x));
      float d2 = (me.w + c.w) - 2.0f*dot;
      unsigned long long key =
        ((unsigned long long)__float_as_uint(d2) << 32) | (unsigned)lane;
      topk = bitonic64(key, lane);
      unsigned long long k15 = __shfl((long long)topk, 15);
      rhs = __uint_as_float((unsigned)(k15 >> 32)) - me.w;
      scan_groups<3>(cand, 1, 0, me, lane, bw, topk, rhs, cnt);
      #pragma unroll 1
      for (int it = 4; it < 32; it += 4)
        scan_groups<4>(cand, it, 0, me, lane, bw, topk, rhs, cnt);
    } else {
      #pragma unroll 1
      for (int it = 0; it < 32; it += 4)
        scan_groups<4>(cand, it, ch, me, lane, bw, topk, rhs, cnt);
    }
  }
  // final drain
  {
    int base = 0;
    while (cnt > 0) {
      int c2 = cnt > 48 ? 48 : cnt;
      unsigned long long e = (lane < 16) ? topk
        : ((lane - 16) < c2 ? bw[base + lane - 16] : ~0ull);
      topk = bitonic64(e, lane);
      base += c2; cnt -= c2;
    }
  }
  if (lane < 16) knn[(q << 4) + lane] = (int)(unsigned)(topk & 0xffffffffu);
}

// ---------------- phase-1 conv-res on MFMA, PERSISTENT (4 tiles/block) ----------------
__global__ __launch_bounds__(512, 4) void k_p1(
    const float4* __restrict__ pts4, const int* __restrict__ knn,
    const unsigned short* __restrict__ wbf,
    const float* __restrict__ a_b, const float* __restrict__ b_b,
    const float* __restrict__ c_b, const float* __restrict__ sc_b,
    unsigned short* __restrict__ X, unsigned short* __restrict__ XM) {
  __shared__ __align__(16) unsigned short Ws1[12288];  // 24 KB swizzled weights
  __shared__ __align__(16) unsigned short Fs[8192];    // 16 KB features
  __shared__ __align__(16) unsigned short Hr[16384];   // 32 KB wave H regions
  const int tid = threadIdx.x;
  const int lane = tid & 63, wv = tid >> 6;
  const int colr = lane & 15, kq = lane >> 4;

  #pragma unroll
  for (int j = 0; j < 3; ++j) {
    int c = j*512 + tid;
    ((uint4*)Ws1)[c] = ((const uint4*)(wbf + 49152))[c];
  }
  const char* WS = (const char*)Ws1;
  char* H = (char*)Hr + wv*4096;

  for (int tile = 0; tile < 4; ++tile) {
    const int bn0 = (blockIdx.x*4 + tile) * 16;
    __syncthreads();
    if (tid < 256) {
      int bnl = tid >> 4, kk = tid & 15;
      int bn = bn0 + bnl;
      int b = bn >> 13;
      float4 cp = pts4[bn];
      int nid = knn[bn*16 + kk];
      float4 np = pts4[(b << 13) + nid];
      float rx = np.x - cp.x, ry = np.y - cp.y, rz = np.z - cp.z;
      float dist = sqrtf(fmaf(rz, rz, fmaf(ry, ry, rx*rx)) + 1e-12f);
      unsigned short row[32];
      row[0]=f2bf(cp.x); row[1]=f2bf(cp.y); row[2]=f2bf(cp.z);
      row[3]=f2bf(np.x); row[4]=f2bf(np.y); row[5]=f2bf(np.z);
      row[6]=f2bf(rx);   row[7]=f2bf(ry);   row[8]=f2bf(rz);   row[9]=f2bf(dist);
      #pragma unroll
      for (int j = 10; j < 32; ++j) row[j] = 0;
      int wvp = tid >> 5, posl = tid & 31;
      char* dst = (char*)Fs + wvp*2048 + posl*64;
      #pragma unroll
      for (int c = 0; c < 4; ++c)
        *(uint4*)(dst + ((c*16) ^ ((posl&3)<<4))) = *(const uint4*)(row + c*8);
    }
    __syncthreads();

    bf16x8 bfr[2];
    #pragma unroll
    for (int ct = 0; ct < 2; ++ct) {
      int posl = ct*16 + colr;
      bfr[ct] = *(const bf16x8*)((const char*)Fs + wv*2048 + posl*64 + ((kq*16) ^ ((posl&3)<<4)));
    }

    f32x4 acc[4][2];
    #pragma unroll
    for (int mt = 0; mt < 4; ++mt) {
      int r0 = mt*16 + kq*4;
      #pragma unroll
      for (int r = 0; r < 4; ++r) {
        float bia = c_b[r0+r] + sc_b[r0+r];
        acc[mt][0][r] = bia; acc[mt][1][r] = bia;
      }
    }
    #pragma unroll
    for (int mt = 0; mt < 4; ++mt) {
      int row = mt*16 + colr;
      bf16x8 w = *(const bf16x8*)(WS + 4096 + row*64 + ((kq*16) ^ ((row&3)<<4)));
      acc[mt][0] = __builtin_amdgcn_mfma_f32_16x16x32_bf16(w, bfr[0], acc[mt][0], 0, 0, 0);
      acc[mt][1] = __builtin_amdgcn_mfma_f32_16x16x32_bf16(w, bfr[1], acc[mt][1], 0, 0, 0);
    }

    f32x4 ha[4][2];
    #pragma unroll
    for (int mt = 0; mt < 4; ++mt) {
      int r0 = mt*16 + kq*4;
      #pragma unroll
      for (int r = 0; r < 4; ++r) { ha[mt][0][r] = a_b[r0+r]; ha[mt][1][r] = a_b[r0+r]; }
    }
    #pragma unroll
    for (int mt = 0; mt < 4; ++mt) {
      int row = mt*16 + colr;
      bf16x8 w = *(const bf16x8*)(WS + row*64 + ((kq*16) ^ ((row&3)<<4)));
      ha[mt][0] = __builtin_amdgcn_mfma_f32_16x16x32_bf16(w, bfr[0], ha[mt][0], 0, 0, 0);
      ha[mt][1] = __builtin_amdgcn_mfma_f32_16x16x32_bf16(w, bfr[1], ha[mt][1], 0, 0, 0);
    }

    #pragma unroll
    for (int mt = 0; mt < 4; ++mt) {
      int ch2 = (mt*16 + kq*4) * 2;
      #pragma unroll
      for (int ct = 0; ct < 2; ++ct) {
        int posl = ct*16 + colr;
        uint2 u;
        u.x = pk2(lk(ha[mt][ct][0]), lk(ha[mt][ct][1]));
        u.y = pk2(lk(ha[mt][ct][2]), lk(ha[mt][ct][3]));
        *(uint2*)(H + posl*128 + (ch2 ^ ((posl&7)<<4))) = u;
      }
    }
    bf16x8 bh[2][2];
    #pragma unroll
    for (int ct = 0; ct < 2; ++ct) {
      int posl = ct*16 + colr;
      #pragma unroll
      for (int k2 = 0; k2 < 2; ++k2)
        bh[ct][k2] = *(const bf16x8*)(H + posl*128 + ((k2*64 + kq*16) ^ ((posl&7)<<4)));
    }

    #pragma unroll
    for (int jj = 0; jj < 2; ++jj) {
      f32x4 h2[2][2];
      #pragma unroll
      for (int mtp = 0; mtp < 2; ++mtp) {
        int r0 = (jj*2 + mtp)*16 + kq*4;
        #pragma unroll
        for (int r = 0; r < 4; ++r) { h2[mtp][0][r] = b_b[r0+r]; h2[mtp][1][r] = b_b[r0+r]; }
      }
      #pragma unroll
      for (int mtp = 0; mtp < 2; ++mtp) {
        int row = (jj*2 + mtp)*16 + colr;
        #pragma unroll
        for (int k2 = 0; k2 < 2; ++k2) {
          bf16x8 w = *(const bf16x8*)(WS + 8192 + row*128 + ((k2*64 + kq*16) ^ ((row&7)<<4)));
          h2[mtp][0] = __builtin_amdgcn_mfma_f32_16x16x32_bf16(w, bh[0][k2], h2[mtp][0], 0, 0, 0);
          h2[mtp][1] = __builtin_amdgcn_mfma_f32_16x16x32_bf16(w, bh[1][k2], h2[mtp][1], 0, 0, 0);
        }
      }
      #pragma unroll
      for (int mtp = 0; mtp < 2; ++mtp) {
        int ch2 = ((jj*2 + mtp)*16 + kq*4) * 2;
        #pragma unroll
        for (int ct = 0; ct < 2; ++ct) {
          int posl = ct*16 + colr;
          uint2 u;
          u.x = pk2(lk(h2[mtp][ct][0]), lk(h2[mtp][ct][1]));
          u.y = pk2(lk(h2[mtp][ct][2]), lk(h2[mtp][ct][3]));
          *(uint2*)(H + posl*128 + (ch2 ^ ((posl&7)<<4))) = u;
        }
      }
      bf16x8 b2[2];
      #pragma unroll
      for (int ct = 0; ct < 2; ++ct) {
        int posl = ct*16 + colr;
        b2[ct] = *(const bf16x8*)(H + posl*128 + ((jj*64 + kq*16) ^ ((posl&7)<<4)));
      }
      #pragma unroll
      for (int mt = 0; mt < 4; ++mt) {
        int row = mt*16 + colr;
        bf16x8 w = *(const bf16x8*)(WS + 16384 + row*128 + ((jj*64 + kq*16) ^ ((row&7)<<4)));
        acc[mt][0] = __builtin_amdgcn_mfma_f32_16x16x32_bf16(w, b2[0], acc[mt][0], 0, 0, 0);
        acc[mt][1] = __builtin_amdgcn_mfma_f32_16x16x32_bf16(w, b2[1], acc[mt][1], 0, 0, 0);
      }
    }

    #pragma unroll
    for (int ct = 0; ct < 2; ++ct) {
      int bn = bn0 + wv*2 + ct;
      #pragma unroll
      for (int mt = 0; mt < 4; ++mt) {
        int ch0 = mt*16 + kq*4;
        uint2 u;
        u.x = pk2(acc[mt][ct][0], acc[mt][ct][1]);
        u.y = pk2(acc[mt][ct][2], acc[mt][ct][3]);
        *(uint2*)(X + ((size_t)(bn*16 + colr))*64 + ch0) = u;
        float m[4];
        #pragma unroll
        for (int r = 0; r < 4; ++r) {
          float v = acc[mt][ct][r];
          v = fmaxf(v, __shfl_xor(v, 1));
          v = fmaxf(v, __shfl_xor(v, 2));
          v = fmaxf(v, __shfl_xor(v, 4));
          v = fmaxf(v, __shfl_xor(v, 8));
          m[r] = v;
        }
        if (colr == 0) {
          uint2 um; um.x = pk2(m[0], m[1]); um.y = pk2(m[2], m[3]);
          *(uint2*)(XM + (size_t)bn*64 + ch0) = um;
        }
      }
    }
  }
}

// ---------------- phase-2 fused MFMA chain, PERSISTENT (8 tiles/block) ----------------
struct P2Shared {
  unsigned short Ws[49152];
  unsigned short Hr[8][2048];
  float outT[128][16];
};

static __device__ __forceinline__ void p2_loadbx(
    bf16x8 (&dst)[2][4], const unsigned short* __restrict__ X,
    const unsigned short* __restrict__ XM, int bn0, int wv, int colr, int kq) {
  #pragma unroll
  for (int ct = 0; ct < 2; ++ct) {
    int bn = bn0 + wv*2 + ct;
    const unsigned short* xr = X + ((size_t)bn*16 + colr)*64 + kq*8;
    dst[ct][0] = *(const bf16x8*)(xr);
    dst[ct][1] = *(const bf16x8*)(xr + 32);
    const unsigned short* mr = XM + (size_t)bn*64 + kq*8;
    dst[ct][2] = *(const bf16x8*)(mr);
    dst[ct][3] = *(const bf16x8*)(mr + 32);
  }
}

__global__ __launch_bounds__(512, 2) void k_p2(
    const unsigned short* __restrict__ X, const unsigned short* __restrict__ XM,
    const unsigned short* __restrict__ wbf,
    const float* __restrict__ sc_b, const float* __restrict__ a_b,
    const float* __restrict__ b_b, const float* __restrict__ c_b,
    float* __restrict__ out) {
  __shared__ __align__(16) P2Shared S;
  const int tid = threadIdx.x;
  const int lane = tid & 63, wv = tid >> 6;
  const int colr = lane & 15, kq = lane >> 4;

  #pragma unroll
  for (int it = 0; it < 12; ++it) {
    int c = it*512 + tid;
    *(uint4*)((char*)S.Ws + c*16) = *(const uint4*)((const char*)wbf + c*16);
  }

  const char* WSC = (const char*)S.Ws;
  const char* WA  = (const char*)(S.Ws + 16384);
  const char* WB  = (const char*)(S.Ws + 24576);
  const char* WC  = (const char*)(S.Ws + 32768);
  char* H = (char*)S.Hr[wv];

#define WF(base, row, K2, ksbyte) \
  (*(const bf16x8*)((base) + (row)*(K2) + ((((ksbyte) + kq*16)) ^ (((row)&7)<<4))))

  bf16x8 bx[2][4], bxn[2][4];
  p2_loadbx(bx, X, XM, blockIdx.x*8*16, wv, colr, kq);
  __syncthreads();

  for (int t = 0; t < 8; ++t) {
    const int bn0 = (blockIdx.x*8 + t) * 16;

    f32x4 acc[8][2];
    #pragma unroll
    for (int mt = 0; mt < 8; ++mt) {
      int r0 = mt*16 + kq*4;
      #pragma unroll
      for (int r = 0; r < 4; ++r) {
        float bia = c_b[r0+r] + sc_b[r0+r];
        acc[mt][0][r] = bia; acc[mt][1][r] = bia;
      }
    }
    #pragma unroll
    for (int mt = 0; mt < 8; ++mt) {
      int row = mt*16 + colr;
      #pragma unroll
      for (int ks = 0; ks < 4; ++ks) {
        bf16x8 w = WF(WSC, row, 256, ks*64);
        acc[mt][0] = __builtin_amdgcn_mfma_f32_16x16x32_bf16(w, bx[0][ks], acc[mt][0], 0, 0, 0);
        acc[mt][1] = __builtin_amdgcn_mfma_f32_16x16x32_bf16(w, bx[1][ks], acc[mt][1], 0, 0, 0);
      }
    }

    f32x4 ha[4][2];
    #pragma unroll
    for (int mt = 0; mt < 4; ++mt) {
      int r0 = mt*16 + kq*4;
      #pragma unroll
      for (int r = 0; r < 4; ++r) { ha[mt][0][r] = a_b[r0+r]; ha[mt][1][r] = a_b[r0+r]; }
    }
    #pragma unroll
    for (int mt = 0; mt < 4; ++mt) {
      int row = mt*16 + colr;
      #pragma unroll
      for (int ks = 0; ks < 4; ++ks) {
        bf16x8 w = WF(WA, row, 256, ks*64);
        ha[mt][0] = __builtin_amdgcn_mfma_f32_16x16x32_bf16(w, bx[0][ks], ha[mt][0], 0, 0, 0);
        ha[mt][1] = __builtin_amdgcn_mfma_f32_16x16x32_bf16(w, bx[1][ks], ha[mt][1], 0, 0, 0);
      }
    }

    {
      int tn = (t < 7) ? (t + 1) : 7;
      p2_loadbx(bxn, X, XM, (blockIdx.x*8 + tn) * 16, wv, colr, kq);
    }

    #pragma unroll
    for (int mt = 0; mt < 4; ++mt) {
      int ch2 = (mt*16 + kq*4) * 2;
      #pragma unroll
      for (int ct = 0; ct < 2; ++ct) {
        int posl = ct*16 + colr;
        uint2 u;
        u.x = pk2(lk(ha[mt][ct][0]), lk(ha[mt][ct][1]));
        u.y = pk2(lk(ha[mt][ct][2]), lk(ha[mt][ct][3]));
        *(uint2*)(H + posl*128 + (ch2 ^ ((posl&7)<<4))) = u;
      }
    }
    bf16x8 bh[2][2];
    #pragma unroll
    for (int ct = 0; ct < 2; ++ct) {
      int posl = ct*16 + colr;
      #pragma unroll
      for (int k2 = 0; k2 < 2; ++k2)
        bh[ct][k2] = *(const bf16x8*)(H + posl*128 + ((k2*64 + kq*16) ^ ((posl&7)<<4)));
    }

    #pragma unroll
    for (int j = 0; j < 4; ++j) {
      f32x4 h2[2][2];
      #pragma unroll
      for (int mtp = 0; mtp < 2; ++mtp) {
        int r0 = (2*j + mtp)*16 + kq*4;
        #pragma unroll
        for (int r = 0; r < 4; ++r) { h2[mtp][0][r] = b_b[r0+r]; h2[mtp][1][r] = b_b[r0+r]; }
      }
      #pragma unroll
      for (int mtp = 0; mtp < 2; ++mtp) {
        int row = (2*j + mtp)*16 + colr;
        #pragma unroll
        for (int k2 = 0; k2 < 2; ++k2) {
          bf16x8 w = WF(WB, row, 128, k2*64);
          h2[mtp][0] = __builtin_amdgcn_mfma_f32_16x16x32_bf16(w, bh[0][k2], h2[mtp][0], 0, 0, 0);
          h2[mtp][1] = __builtin_amdgcn_mfma_f32_16x16x32_bf16(w, bh[1][k2], h2[mtp][1], 0, 0, 0);
        }
      }
      char* PB = H + (j & 1)*2048;
      #pragma unroll
      for (int mtp = 0; mtp < 2; ++mtp) {
        int chp2 = (mtp*16 + kq*4) * 2;
        #pragma unroll
        for (int ct = 0; ct < 2; ++ct) {
          int posl = ct*16 + colr;
          uint2 u;
          u.x = pk2(lk(h2[mtp][ct][0]), lk(h2[mtp][ct][1]));
          u.y = pk2(lk(h2[mtp][ct][2]), lk(h2[mtp][ct][3]));
          *(uint2*)(PB + posl*64 + (chp2 ^ ((posl&3)<<4))) = u;
        }
      }
      bf16x8 b2[2];
      #pragma unroll
      for (int ct = 0; ct < 2; ++ct) {
        int posl = ct*16 + colr;
        b2[ct] = *(const bf16x8*)(PB + posl*64 + ((kq*16) ^ ((posl&3)<<4)));
      }
      #pragma unroll
      for (int mt = 0; mt < 8; ++mt) {
        int row = mt*16 + colr;
        bf16x8 w = WF(WC, row, 256, j*64);
        acc[mt][0] = __builtin_amdgcn_mfma_f32_16x16x32_bf16(w, b2[0], acc[mt][0], 0, 0, 0);
        acc[mt][1] = __builtin_amdgcn_mfma_f32_16x16x32_bf16(w, b2[1], acc[mt][1], 0, 0, 0);
      }
    }

    __syncthreads();
    #pragma unroll
    for (int mt = 0; mt < 8; ++mt) {
      #pragma unroll
      for (int ct = 0; ct < 2; ++ct) {
        #pragma unroll
        for (int r = 0; r < 4; ++r) {
          float v = acc[mt][ct][r];
          v = fmaxf(v, __shfl_xor(v, 1));
          v = fmaxf(v, __shfl_xor(v, 2));
          v = fmaxf(v, __shfl_xor(v, 4));
          v = fmaxf(v, __shfl_xor(v, 8));
          if (colr == 0) S.outT[mt*16 + kq*4 + r][wv*2 + ct] = v;
        }
      }
    }
    __syncthreads();
    {
      int ch = tid >> 2, p = tid & 3;
      int b = bn0 >> 13, n0 = bn0 & (N_-1);
      float4 v4 = *(const float4*)&S.outT[ch][p*4];
      *(float4*)(out + ((size_t)b*128 + ch)*N_ + n0 + p*4) = v4;
    }

    #pragma unroll
    for (int ct = 0; ct < 2; ++ct)
      #pragma unroll
      for (int ks = 0; ks < 4; ++ks)
        bx[ct][ks] = bxn[ct][ks];
  }
#undef WF
}

extern "C" void kernel_launch(void* const* d_in, const int* in_sizes, int n_in,
                              void* d_out, int out_size, void* d_ws, size_t ws_size,
                              hipStream_t stream) {
  const float* xyz     = (const float*)d_in[0];
  const float* p1_sc_w = (const float*)d_in[1];
  const float* p1_sc_b = (const float*)d_in[2];
  const float* p1_a_w  = (const float*)d_in[3];
  const float* p1_a_b  = (const float*)d_in[4];
  const float* p1_b_w  = (const float*)d_in[5];
  const float* p1_b_b  = (const float*)d_in[6];
  const float* p1_c_w  = (const float*)d_in[7];
  const float* p1_c_b  = (const float*)d_in[8];
  const float* p2_sc_w = (const float*)d_in[9];
  const float* p2_sc_b = (const float*)d_in[10];
  const float* p2_a_w  = (const float*)d_in[11];
  const float* p2_a_b  = (const float*)d_in[12];
  const float* p2_b_w  = (const float*)d_in[13];
  const float* p2_b_b  = (const float*)d_in[14];
  const float* p2_c_w  = (const float*)d_in[15];
  const float* p2_c_b  = (const float*)d_in[16];

  if (ws_size < 75497472u) return;  // need ~72 MB scratch
  char* ws = (char*)d_ws;
  float4* pts4        = (float4*)(ws);
  unsigned short* wbf = (unsigned short*)(ws + 524288);
  int* knn            = (int*)(ws + 655360);
  unsigned short* X   = (unsigned short*)(ws + 4194304);
  unsigned short* XM  = (unsigned short*)(ws + 4194304 + 67108864);
  float* out = (float*)d_out;

  k_prep<<<dim3(BN_/256), dim3(256), 0, stream>>>(xyz, pts4);
  k_wcvt<<<dim3(240), dim3(256), 0, stream>>>(p2_sc_w, p2_a_w, p2_b_w, p2_c_w,
      p1_a_w, p1_sc_w, p1_b_w, p1_c_w, wbf);
  k_knn<<<dim3(BN_/8), dim3(512), 0, stream>>>(pts4, knn);
  k_p1<<<dim3(512), dim3(512), 0, stream>>>(pts4, knn, wbf,
      p1_a_b, p1_b_b, p1_c_b, p1_sc_b, X, XM);
  k_p2<<<dim3(256), dim3(512), 0, stream>>>(X, XM, wbf,
      p2_sc_b, p2_a_b, p2_b_b, p2_c_b, out);
}